// Round 9
// baseline (16117.938 us; speedup 1.0000x reference)
//
#include <hip/hip_runtime.h>
#include <hip/hip_bf16.h>
#include <math.h>

#define BB 128
#define TT 512
#define U  512
#define G  2048   // 4*U
#define WPG 32    // WGs per barrier group (col-split of one row-tile)

typedef short short8 __attribute__((ext_vector_type(8)));
typedef float floatx4 __attribute__((ext_vector_type(4)));

__device__ __forceinline__ float sigmoidf_(float x) {
    return 1.0f / (1.0f + __expf(-x));
}
__device__ __forceinline__ float tanhf_(float v) {
    float e = __expf(2.0f * v);
    return 1.0f - 2.0f / (e + 1.0f);
}

// ---------------- prep: Wh [512][2048] -> WhPT [d][c][k] bf16, c = u*4+g ----
__global__ __launch_bounds__(256)
void prep_wh(const float* __restrict__ Wh_f, const float* __restrict__ Wh_b,
             __hip_bfloat16* __restrict__ WhPT)
{
    const int kt = blockIdx.x, ct = blockIdx.y, d = blockIdx.z;
    const float* Wh = d ? Wh_b : Wh_f;
    const int tx = threadIdx.x & 31, ty = threadIdx.x >> 5;
    __shared__ float tile[32][33];
    #pragma unroll
    for (int i = 0; i < 4; ++i) {
        int r = ty + 8 * i;
        tile[r][tx] = Wh[(size_t)(kt * 32 + r) * G + ct * 32 + tx];
    }
    __syncthreads();
    #pragma unroll
    for (int i = 0; i < 4; ++i) {
        int colLocal = ty + 8 * i;
        int col = ct * 32 + colLocal;             // original col: g*512+u
        int c = ((col & 511) << 2) | (col >> 9);  // u*4+g
        WhPT[((size_t)d * G + c) * U + kt * 32 + tx] =
            __float2bfloat16(tile[tx][colLocal]);
    }
}

// ---------------- prep: WxbP [d][4][c] fp32 (rows 0..2 = Wx, row 3 = bias) --
__global__ __launch_bounds__(256)
void prep_wxb(const float* __restrict__ Wx_f, const float* __restrict__ b_f,
              const float* __restrict__ Wx_b, const float* __restrict__ b_b,
              float* __restrict__ WxbP)
{
    int idx = blockIdx.x * blockDim.x + threadIdx.x;
    if (idx >= 2 * G) return;
    int d = idx / G, c = idx % G;
    const float* Wx = d ? Wx_b : Wx_f;
    const float* bb = d ? b_b  : b_f;
    int col = ((c & 3) << 9) | (c >> 2);               // g*512+u
    WxbP[((size_t)d * 4 + 0) * G + c] = Wx[0 * G + col];
    WxbP[((size_t)d * 4 + 1) * G + c] = Wx[1 * G + col];
    WxbP[((size_t)d * 4 + 2) * G + c] = Wx[2 * G + col];
    WxbP[((size_t)d * 4 + 3) * G + c] = bb[col];
}

// ------------ init: zero h (both phases), c (fallback), barrier counters ----
__global__ void init_state(__hip_bfloat16* h, float* c, int* cnt,
                           int nh, int nc, int ncnt)
{
    int i = blockIdx.x * blockDim.x + threadIdx.x;
    if (i < nh) h[i] = __float2bfloat16(0.0f);
    if (i < nc) c[i] = 0.0f;
    if (i < ncnt) cnt[i] = 0;
}

// ================= persistent kernel with group barriers ===================
// grid: 256 WGs x 256 thr = 1 WG/CU (co-resident via cooperative launch).
// WG (rt = wg>>5, cw = wg&31): rows rt*16..+16, permuted cols cw*64..+64
// (= units cw*16..+16), BOTH directions. Wave w: 16 cols. Wh fragments for
// both dirs pinned in VGPRs (asm liveness). c/h state in registers.
// Barrier groups: (rt, dir) -> 32 WGs, counter cnt[(rt*2+dir)*64].
__global__ __launch_bounds__(256, 1)
void lstm_chain(const float* __restrict__ x,       // [BB][TT][3]
                const int*   __restrict__ mask,    // [BB][TT]
                const __hip_bfloat16* __restrict__ WhPT,  // [2][G][U]
                const float* __restrict__ WxbP,    // [2][4][G]
                __hip_bfloat16* __restrict__ hbuf, // [2 ph][2 d][BB][U]
                int* __restrict__ cnt,
                float* __restrict__ out)
{
    const int wg  = blockIdx.x;
    const int rt  = wg >> 5;
    const int cw  = wg & 31;
    const int tid = threadIdx.x;
    const int w   = tid >> 6;
    const int l   = tid & 63;
    const int W0  = cw * 64;

    // ---- persistent B fragments, both dirs: 32 x short8 = 128 VGPR ----
    const int bcol = W0 + w * 16 + (l & 15);
    const int g8   = (l >> 4) * 8;
    short8 bfF[16], bfB[16];
    {
        const short* BpF = (const short*)WhPT;
        const short* BpB = BpF + (size_t)G * U;
        #pragma unroll
        for (int kk = 0; kk < 16; ++kk) {
            bfF[kk] = *(const short8*)(BpF + (size_t)bcol * U + kk * 32 + g8);
            bfB[kk] = *(const short8*)(BpB + (size_t)bcol * U + kk * 32 + g8);
        }
        #pragma unroll
        for (int kk = 0; kk < 16; ++kk)
            asm volatile("" : "+v"(bfF[kk]), "+v"(bfB[kk]));
    }

    // ---- epilogue mapping + Wx/bias fragments ----
    const int er = tid >> 4;            // row-local
    const int ul = tid & 15;            // unit-local
    const int eb = rt * 16 + er;        // batch row
    const int eu = cw * 16 + ul;        // global unit
    const int c4 = W0 + ul * 4;
    floatx4 wxF[4], wxB[4];
    #pragma unroll
    for (int i = 0; i < 4; ++i) {
        wxF[i] = *(const floatx4*)(WxbP + (size_t)i * G + c4);
        wxB[i] = *(const floatx4*)(WxbP + (size_t)(4 + i) * G + c4);
    }

    __shared__ char  At[16 * 1024];     // 16 rows x 512 bf16, XOR-swizzled
    __shared__ float zt[16][68];

    float hF = 0.f, cF = 0.f, hB = 0.f, cB = 0.f;
    int* pF = cnt + (rt * 2 + 0) * 64;
    int* pB = cnt + (rt * 2 + 1) * 64;

    const int PH = 2 * BB * U;
    float* sh = out + (size_t)BB * TT * 1024;   // state_h [BB][2][U]
    float* sc = sh + (size_t)BB * 2 * U;        // state_c [BB][2][U]

    for (int t = 0; t < TT; ++t) {
        const int ph = t & 1;

        #pragma unroll
        for (int d = 0; d < 2; ++d) {
            // ---- wait for this dir's h(t) (group barrier of step t-1) ----
            int* pc = d ? pB : pF;
            if (t > 0) {
                if (tid == 0) {
                    while (__hip_atomic_load(pc, __ATOMIC_RELAXED,
                                             __HIP_MEMORY_SCOPE_AGENT) < WPG * t)
                        __builtin_amdgcn_s_sleep(1);
                }
                __syncthreads();
                (void)__hip_atomic_load(pc, __ATOMIC_ACQUIRE,
                                        __HIP_MEMORY_SCOPE_AGENT);
            }

            const int tau = d ? (TT - 1 - t) : t;
            const __hip_bfloat16* hsrc =
                hbuf + (size_t)ph * PH + (size_t)d * BB * U + (size_t)rt * 16 * U;
            __hip_bfloat16* hdst =
                hbuf + (size_t)(ph ^ 1) * PH + (size_t)d * BB * U;

            // ---- stage 16 rows x 512 k (16 KB) into swizzled LDS ----
            __syncthreads();   // all waves done with At/zt from previous phase
            #pragma unroll
            for (int i = 0; i < 4; ++i) {
                int idx = i * 256 + tid;
                int row = idx >> 6, kc = idx & 63;
                short8 v = *(const short8*)((const short*)hsrc + row * U + kc * 8);
                int byte = (row * 1024 + kc * 16) ^ ((row & 15) << 4);
                *(short8*)(At + byte) = v;
            }
            __syncthreads();

            // ---- MFMA: 16 rows x 16 cols, K=512 ----
            {
                floatx4 acc = {0.f, 0.f, 0.f, 0.f};
                const int r = l & 15;
                const short8* bf = d ? bfB : bfF;
                #pragma unroll
                for (int kk = 0; kk < 16; ++kk) {
                    int chunk = kk * 4 + (l >> 4);
                    int byte = (r * 1024 + chunk * 16) ^ ((r & 15) << 4);
                    short8 a = *(const short8*)(At + byte);
                    acc = __builtin_amdgcn_mfma_f32_16x16x32_bf16(a, bf[kk], acc, 0, 0, 0);
                }
                int rl = (l >> 4) * 4, cl = w * 16 + (l & 15);
                #pragma unroll
                for (int j = 0; j < 4; ++j) zt[rl + j][cl] = acc[j];
            }
            __syncthreads();

            // ---- epilogue: one (row, unit) per thread ----
            {
                floatx4 zz = *(const floatx4*)&zt[er][ul * 4];
                const floatx4* wx = d ? wxB : wxF;
                const float* xr = x + ((size_t)eb * TT + tau) * 3;
                float x0 = xr[0], x1 = xr[1], x2 = xr[2];

                float zi = zz[0] + x0 * wx[0][0] + x1 * wx[1][0] + x2 * wx[2][0] + wx[3][0];
                float zf = zz[1] + x0 * wx[0][1] + x1 * wx[1][1] + x2 * wx[2][1] + wx[3][1];
                float zg = zz[2] + x0 * wx[0][2] + x1 * wx[1][2] + x2 * wx[2][2] + wx[3][2];
                float zo = zz[3] + x0 * wx[0][3] + x1 * wx[1][3] + x2 * wx[2][3] + wx[3][3];

                float ig = sigmoidf_(zi);
                float fg = sigmoidf_(zf);
                float gg = tanhf_(zg);
                float og = sigmoidf_(zo);

                float hprev = d ? hB : hF;
                float cprev = d ? cB : cF;
                float cn = fg * cprev + ig * gg;
                float hv = og * tanhf_(cn);
                bool  m  = (mask[(size_t)eb * TT + tau] != 0);
                float h2 = m ? hv : hprev;
                float c2 = m ? cn : cprev;
                if (d) { hB = h2; cB = c2; } else { hF = h2; cF = c2; }

                hdst[(size_t)eb * U + eu] = __float2bfloat16(h2);
                out[((size_t)eb * TT + tau) * 1024 + d * 512 + eu] = h2;
            }

            // ---- arrive: release this dir's h(t+1) ----
            __syncthreads();   // all threads' stores drained to L2
            if (tid == 0)
                __hip_atomic_fetch_add(pc, 1, __ATOMIC_RELEASE,
                                       __HIP_MEMORY_SCOPE_AGENT);
        }
    }

    // final states (exact fp32 from registers)
    sh[(size_t)eb * 1024 + 0 * 512 + eu] = hF;
    sh[(size_t)eb * 1024 + 1 * 512 + eu] = hB;
    sc[(size_t)eb * 1024 + 0 * 512 + eu] = cF;
    sc[(size_t)eb * 1024 + 1 * 512 + eu] = cB;
}

// ---------------- pos_agg from fp32 state_h (chain path) -------------------
__global__ __launch_bounds__(64)
void finalize_pos(const float* __restrict__ W1, const float* __restrict__ b1,
                  float* __restrict__ out)
{
    const int b = blockIdx.x;
    const int tid = threadIdx.x;
    const float* sh = out + (size_t)BB * TT * 1024;
    float* pa = out + (size_t)BB * TT * 1024 + 2 * (size_t)BB * 2 * U;
    __shared__ float red[8][8];
    {
        int j = tid & 7, seg = tid >> 3;
        int jj = j & 3;
        const float* hv = sh + (size_t)b * 1024 + (j >> 2) * 512;
        float s = 0.f;
        for (int u = seg * 64; u < seg * 64 + 64; ++u)
            s = fmaf(hv[u], W1[u * 4 + jj], s);
        red[seg][j] = s;
    }
    __syncthreads();
    if (tid < 8) {
        float s = b1[tid & 3];
        #pragma unroll
        for (int seg = 0; seg < 8; ++seg) s += red[seg][tid];
        pa[b * 8 + tid] = s;
    }
}

// ================= fallback path (proven R4): per-step kernel ==============
__global__ __launch_bounds__(64)
void lstm_step(const float* __restrict__ x,
               const int*   __restrict__ mask,
               const __hip_bfloat16* __restrict__ WhPT,
               const float* __restrict__ WxbP,
               const __hip_bfloat16* __restrict__ hr,
               __hip_bfloat16*       __restrict__ hw,
               float*       __restrict__ cws,
               float*       __restrict__ out,
               int t)
{
    const int ct = blockIdx.x;
    const int rt = blockIdx.y;
    const int d  = blockIdx.z;
    const int l  = threadIdx.x;
    const int tau = d ? (TT - 1 - t) : t;

    const short* A  = (const short*)(hr + (size_t)d * BB * U);
    const short* Bp = (const short*)(WhPT + (size_t)d * G * U);
    const int r0 = rt * 16;
    const int c0 = ct * 32;

    const int arow = r0 + (l & 15);
    const int kofs = (l >> 4) * 8;
    const int bc0  = c0 + (l & 15);

    floatx4 acc0 = {0.f, 0.f, 0.f, 0.f};
    floatx4 acc1 = {0.f, 0.f, 0.f, 0.f};

    #pragma unroll
    for (int kk = 0; kk < 16; ++kk) {
        int k = kk * 32 + kofs;
        short8 a  = *(const short8*)(A  + (size_t)arow * U + k);
        short8 b0 = *(const short8*)(Bp + (size_t)bc0        * U + k);
        short8 b1 = *(const short8*)(Bp + (size_t)(bc0 + 16) * U + k);
        acc0 = __builtin_amdgcn_mfma_f32_16x16x32_bf16(a, b0, acc0, 0, 0, 0);
        acc1 = __builtin_amdgcn_mfma_f32_16x16x32_bf16(a, b1, acc1, 0, 0, 0);
    }

    __shared__ float z[16][36];
    {
        int rl = (l >> 4) * 4;
        int cl = l & 15;
        #pragma unroll
        for (int j = 0; j < 4; ++j) {
            z[rl + j][cl]      = acc0[j];
            z[rl + j][cl + 16] = acc1[j];
        }
    }
    __syncthreads();

    const float* WxbD = WxbP + (size_t)d * 4 * G;
    #pragma unroll
    for (int p = 0; p < 2; ++p) {
        int row = l & 15;
        int un  = (l >> 4) + 4 * p;
        int b   = r0 + row;
        int u   = ct * 8 + un;
        int c4  = c0 + un * 4;

        floatx4 zz  = *(const floatx4*)&z[row][un * 4];
        floatx4 wx0 = *(const floatx4*)(WxbD + 0 * G + c4);
        floatx4 wx1 = *(const floatx4*)(WxbD + 1 * G + c4);
        floatx4 wx2 = *(const floatx4*)(WxbD + 2 * G + c4);
        floatx4 wb  = *(const floatx4*)(WxbD + 3 * G + c4);

        const float* xr = x + ((size_t)b * TT + tau) * 3;
        float x0 = xr[0], x1 = xr[1], x2 = xr[2];

        float zi = zz[0] + x0 * wx0[0] + x1 * wx1[0] + x2 * wx2[0] + wb[0];
        float zf = zz[1] + x0 * wx0[1] + x1 * wx1[1] + x2 * wx2[1] + wb[1];
        float zg = zz[2] + x0 * wx0[2] + x1 * wx1[2] + x2 * wx2[2] + wb[2];
        float zo = zz[3] + x0 * wx0[3] + x1 * wx1[3] + x2 * wx2[3] + wb[3];

        float ig = sigmoidf_(zi);
        float fg = sigmoidf_(zf);
        float gg = tanhf_(zg);
        float og = sigmoidf_(zo);

        size_t su = (size_t)d * BB * U + (size_t)b * U + u;
        float cprev = cws[su];
        float hprev = __bfloat162float(hr[su]);
        float cn = fg * cprev + ig * gg;
        float hn = og * tanhf_(cn);
        bool  m  = (mask[(size_t)b * TT + tau] != 0);
        float h2 = m ? hn : hprev;
        float c2 = m ? cn : cprev;
        cws[su] = c2;
        hw[su]  = __float2bfloat16(h2);
        out[((size_t)b * TT + tau) * 1024 + d * 512 + u] = h2;
    }
}

__global__ __launch_bounds__(256)
void finalize(const __hip_bfloat16* __restrict__ hfin,
              const float* __restrict__ cfin,
              const float* __restrict__ W1,
              const float* __restrict__ b1,
              float* __restrict__ out)
{
    const int b = blockIdx.x;
    const int tid = threadIdx.x;
    float* sh = out + (size_t)BB * TT * 1024;
    float* sc = sh + (size_t)BB * 2 * U;
    float* pa = sc + (size_t)BB * 2 * U;
    for (int i = tid; i < 2 * U; i += 256) {
        int d = i / U, u = i % U;
        sh[(size_t)b * 2 * U + i] = __bfloat162float(hfin[(size_t)d * BB * U + b * U + u]);
        sc[(size_t)b * 2 * U + i] = cfin[(size_t)d * BB * U + b * U + u];
    }
    __shared__ float red[8][8];
    if (tid < 64) {
        int j = tid & 7;
        int seg = tid >> 3;
        int dd = j >> 2, jj = j & 3;
        const __hip_bfloat16* hv = hfin + (size_t)dd * BB * U + (size_t)b * U;
        float s = 0.f;
        for (int u = seg * 64; u < seg * 64 + 64; ++u)
            s = fmaf(__bfloat162float(hv[u]), W1[u * 4 + jj], s);
        red[seg][j] = s;
    }
    __syncthreads();
    if (tid < 8) {
        float s = b1[tid & 3];
        #pragma unroll
        for (int seg = 0; seg < 8; ++seg) s += red[seg][tid];
        pa[b * 8 + tid] = s;
    }
}

extern "C" void kernel_launch(void* const* d_in, const int* in_sizes, int n_in,
                              void* d_out, int out_size, void* d_ws, size_t ws_size,
                              hipStream_t stream)
{
    (void)in_sizes; (void)n_in; (void)out_size; (void)ws_size;
    const float* x    = (const float*)d_in[0];
    const int*   mask = (const int*)d_in[1];
    const float* Wx_f = (const float*)d_in[2];
    const float* Wh_f = (const float*)d_in[3];
    const float* b_f  = (const float*)d_in[4];
    const float* Wx_b = (const float*)d_in[5];
    const float* Wh_b = (const float*)d_in[6];
    const float* b_b  = (const float*)d_in[7];
    const float* W1   = (const float*)d_in[8];
    const float* b1   = (const float*)d_in[9];
    float* out = (float*)d_out;

    char* wsb = (char*)d_ws;
    __hip_bfloat16* WhPT = (__hip_bfloat16*)wsb;                 wsb += (size_t)2 * G * U * 2;
    float*          WxbP = (float*)wsb;                          wsb += (size_t)2 * 4 * G * 4;
    __hip_bfloat16* hbuf = (__hip_bfloat16*)wsb;                 wsb += (size_t)2 * 2 * BB * U * 2;
    float*          cbuf = (float*)wsb;                          wsb += (size_t)2 * BB * U * 4;
    int*            cnt  = (int*)wsb;                            // 1024 ints

    const int PH = 2 * BB * U;

    prep_wh<<<dim3(16, 64, 2), 256, 0, stream>>>(Wh_f, Wh_b, WhPT);
    prep_wxb<<<(2 * G + 255) / 256, 256, 0, stream>>>(Wx_f, b_f, Wx_b, b_b, WxbP);
    init_state<<<(2 * PH + 255) / 256, 256, 0, stream>>>(hbuf, cbuf, cnt,
                                                         2 * PH, PH, 1024);

    // ---- preferred: persistent kernel, custom group barriers ----
    {
        const float* xa = x; const int* ma = mask;
        const __hip_bfloat16* wh = WhPT; const float* wx = WxbP;
        __hip_bfloat16* hb = hbuf; int* cn = cnt; float* oo = out;
        void* args[] = { (void*)&xa, (void*)&ma, (void*)&wh, (void*)&wx,
                         (void*)&hb, (void*)&cn, (void*)&oo };
        hipError_t err = hipLaunchCooperativeKernel(
            (const void*)lstm_chain, dim3(256), dim3(256), args, 0, stream);
        if (err == hipSuccess) {
            finalize_pos<<<BB, 64, 0, stream>>>(W1, b1, out);
            return;
        }
        (void)hipGetLastError();   // clear error, fall through to fallback
    }

    // ---- fallback: proven per-step loop (R4) ----
    dim3 grid(64, 8, 2), block(64);
    for (int t = 0; t < TT; ++t) {
        const __hip_bfloat16* hrp = hbuf + (size_t)(t & 1) * PH;
        __hip_bfloat16*       hwp = hbuf + (size_t)((t + 1) & 1) * PH;
        lstm_step<<<grid, block, 0, stream>>>(x, mask, WhPT, WxbP,
                                              hrp, hwp, cbuf, out, t);
    }
    finalize<<<BB, 256, 0, stream>>>(hbuf, cbuf, W1, b1, out);
}